// Round 1
// 987.437 us; speedup vs baseline: 1.2962x; 1.2962x over previous
//
#include <hip/hip_runtime.h>

#define NUM_USERS 100000
#define NUM_ITEMS 150000
#define N_NODES   250000
#define DIM       64
#define N_EDGES   2000000
#define EPS       0.2

#define SCAN_BS 1024
#define SCAN_NB ((N_NODES + SCAN_BS - 1) / SCAN_BS)   // 245

// ---------------------------------------------------------------------------
// init: E(fp32) = concat(user_emb, item_emb), float4-vectorized
// ---------------------------------------------------------------------------
__global__ void init_kernel(const float4* __restrict__ user,
                            const float4* __restrict__ item,
                            float4* __restrict__ E) {
    int i = blockIdx.x * blockDim.x + threadIdx.x;
    const int userN4 = NUM_USERS * DIM / 4;   // 1.6M
    const int total4 = N_NODES * DIM / 4;     // 4M
    if (i >= total4) return;
    E[i] = (i < userN4) ? user[i] : item[i - userN4];
}

// ---------------------------------------------------------------------------
// CSR build: histogram of dst
// ---------------------------------------------------------------------------
__global__ void hist_kernel(const int* __restrict__ dst, int* __restrict__ counts) {
    int e = blockIdx.x * blockDim.x + threadIdx.x;
    if (e >= N_EDGES) return;
    atomicAdd(&counts[dst[e]], 1);
}

// in-place inclusive scan per 1024-block; block totals -> bsums
__global__ void scan_block(int* __restrict__ data, int* __restrict__ bsums) {
    __shared__ int tmp[SCAN_BS];
    int gid = blockIdx.x * SCAN_BS + threadIdx.x;
    int v = (gid < N_NODES) ? data[gid] : 0;
    tmp[threadIdx.x] = v;
    __syncthreads();
    for (int off = 1; off < SCAN_BS; off <<= 1) {
        int t = (threadIdx.x >= off) ? tmp[threadIdx.x - off] : 0;
        __syncthreads();
        tmp[threadIdx.x] += t;
        __syncthreads();
    }
    if (gid < N_NODES) data[gid] = tmp[threadIdx.x];
    if (threadIdx.x == SCAN_BS - 1) bsums[blockIdx.x] = tmp[SCAN_BS - 1];
}

// exclusive scan of the 245 block sums (tiny; one thread)
__global__ void scan_bsums(int* __restrict__ bsums) {
    if (threadIdx.x == 0 && blockIdx.x == 0) {
        int run = 0;
        for (int i = 0; i < SCAN_NB; ++i) { int t = bsums[i]; bsums[i] = run; run += t; }
    }
}

// row_ptr[i+1] = incl[i] + bsums[block(i)]; row_ptr[0] = 0
__global__ void scan_finalize(const int* __restrict__ incl, const int* __restrict__ bsums,
                              int* __restrict__ row_ptr) {
    int gid = blockIdx.x * SCAN_BS + threadIdx.x;
    if (gid < N_NODES) row_ptr[gid + 1] = incl[gid] + bsums[gid >> 10];
    if (gid == 0) row_ptr[0] = 0;
}

// scatter edges into CSR slots; pack {src, val} into one int2
__global__ void fill_kernel(const int* __restrict__ src, const int* __restrict__ dst,
                            const float* __restrict__ vals,
                            const int* __restrict__ row_ptr, int* __restrict__ fill,
                            int2* __restrict__ edges) {
    int e = blockIdx.x * blockDim.x + threadIdx.x;
    if (e >= N_EDGES) return;
    int d = dst[e];
    int pos = row_ptr[d] + atomicAdd(&fill[d], 1);
    edges[pos] = make_int2(src[e], __float_as_int(vals[e]));
}

// ---------------------------------------------------------------------------
// fused layer: one 64-lane wave per node (lane == dim)
//   seg = sum over in-edges of val * Ain[src][lane]   (fp32 loads, fp64 accum)
//   ne  = seg + sign(seg) * l2norm(noise_row) * EPS
//   MODE 0: Aout = ne; cl_out = l2norm(ne)
//   MODE 1: Aout = ne
//   MODE 2: a = E + B1 + Ain(=B2) + ne; out = l2norm(a)   (no Aout)
// ---------------------------------------------------------------------------
template<int MODE>
__global__ void layer_kernel(const float* __restrict__ Ain,
                             float* __restrict__ Aout,
                             const int* __restrict__ row_ptr,
                             const int2* __restrict__ edges,
                             const float* __restrict__ noise,
                             const float* __restrict__ E,
                             const float* __restrict__ B1,
                             float* __restrict__ out,
                             float* __restrict__ cl_out) {
    int node = blockIdx.x * 4 + (threadIdx.x >> 6);
    int lane = threadIdx.x & 63;
    if (node >= N_NODES) return;
    long long base = (long long)node * DIM + lane;

    int beg = row_ptr[node];
    int end = row_ptr[node + 1];

    double s0 = 0.0, s1 = 0.0, s2 = 0.0, s3 = 0.0;
    int j = beg;
    for (; j + 3 < end; j += 4) {
        int2 e0 = edges[j];
        int2 e1 = edges[j + 1];
        int2 e2 = edges[j + 2];
        int2 e3 = edges[j + 3];
        s0 += (double)__int_as_float(e0.y) * (double)Ain[(long long)e0.x * DIM + lane];
        s1 += (double)__int_as_float(e1.y) * (double)Ain[(long long)e1.x * DIM + lane];
        s2 += (double)__int_as_float(e2.y) * (double)Ain[(long long)e2.x * DIM + lane];
        s3 += (double)__int_as_float(e3.y) * (double)Ain[(long long)e3.x * DIM + lane];
    }
    for (; j < end; ++j) {
        int2 e0 = edges[j];
        s0 += (double)__int_as_float(e0.y) * (double)Ain[(long long)e0.x * DIM + lane];
    }
    double seg = (s0 + s1) + (s2 + s3);

    // noise row l2norm (stream-once data: bypass LLC)
    float nzf = __builtin_nontemporal_load(noise + base);
    double nz = (double)nzf;
    double ss = nz * nz;
    #pragma unroll
    for (int off = 32; off; off >>= 1) ss += __shfl_xor(ss, off);
    double nrm = nz * (1.0 / sqrt(fmax(ss, 1e-24)));

    double sg = (seg > 0.0) ? 1.0 : ((seg < 0.0) ? -1.0 : 0.0);
    double ne = seg + sg * nrm * EPS;

    if (MODE != 2) Aout[base] = (float)ne;

    if (MODE == 0) {
        double s2n = ne * ne;
        #pragma unroll
        for (int off = 32; off; off >>= 1) s2n += __shfl_xor(s2n, off);
        __builtin_nontemporal_store((float)(ne * (1.0 / sqrt(fmax(s2n, 1e-24)))),
                                    cl_out + base);
    }

    if (MODE == 2) {
        double a = (double)E[base] + (double)B1[base] + (double)Ain[base] + ne;
        double s3n = a * a;
        #pragma unroll
        for (int off = 32; off; off >>= 1) s3n += __shfl_xor(s3n, off);
        __builtin_nontemporal_store((float)(a * (1.0 / sqrt(fmax(s3n, 1e-24)))),
                                    out + base);
    }
}

extern "C" void kernel_launch(void* const* d_in, const int* in_sizes, int n_in,
                              void* d_out, int out_size, void* d_ws, size_t ws_size,
                              hipStream_t stream) {
    const float* user  = (const float*)d_in[0];
    const float* item  = (const float*)d_in[1];
    const float* vals  = (const float*)d_in[2];
    const float* noise = (const float*)d_in[3];
    const int*   src   = (const int*)d_in[4];
    const int*   dst   = (const int*)d_in[5];

    float* out = (float*)d_out;
    float* acc = out;                                  // 16M fp32 (users+items normalized)
    float* cl  = out + (long long)N_NODES * DIM;       // 16M fp32 (cl region)

    char* p = (char*)d_ws;
    float* E  = (float*)p;  p += (size_t)N_NODES * DIM * sizeof(float);   // 64 MB
    float* B1 = (float*)p;  p += (size_t)N_NODES * DIM * sizeof(float);   // 64 MB
    float* B2 = (float*)p;  p += (size_t)N_NODES * DIM * sizeof(float);   // 64 MB
    int* row_ptr = (int*)p;   p += ((size_t)(N_NODES + 1) * 4 + 255) & ~255ull;
    int* fill    = (int*)p;   p += ((size_t)N_NODES * 4 + 255) & ~255ull;
    int* bsums   = (int*)p;   p += 4096;
    int2* edges  = (int2*)p;                                              // 16 MB

    const int edgeBlocks = (N_EDGES + 255) / 256;      // 7813
    const int total4 = N_NODES * DIM / 4;              // 4M

    // --- CSR build ---
    hipMemsetAsync(fill, 0, (size_t)N_NODES * 4, stream);
    hist_kernel<<<edgeBlocks, 256, 0, stream>>>(dst, fill);
    scan_block<<<SCAN_NB, SCAN_BS, 0, stream>>>(fill, bsums);
    scan_bsums<<<1, 64, 0, stream>>>(bsums);
    scan_finalize<<<SCAN_NB, SCAN_BS, 0, stream>>>(fill, bsums, row_ptr);
    hipMemsetAsync(fill, 0, (size_t)N_NODES * 4, stream);
    fill_kernel<<<edgeBlocks, 256, 0, stream>>>(src, dst, vals, row_ptr, fill, edges);

    // --- init embeddings (fp32) ---
    init_kernel<<<(total4 + 255) / 256, 256, 0, stream>>>(
        (const float4*)user, (const float4*)item, (float4*)E);

    // --- 3 fused layers: E -> B1 -> B2 -> (finalize) ---
    const int layerBlocks = (N_NODES + 3) / 4;         // 62500 (4 waves/block)
    const float* n0 = noise;
    const float* n1 = noise + (long long)N_NODES * DIM;
    const float* n2 = noise + 2LL * N_NODES * DIM;
    layer_kernel<0><<<layerBlocks, 256, 0, stream>>>(E,  B1, row_ptr, edges, n0,
                                                     nullptr, nullptr, nullptr, cl);
    layer_kernel<1><<<layerBlocks, 256, 0, stream>>>(B1, B2, row_ptr, edges, n1,
                                                     nullptr, nullptr, nullptr, nullptr);
    layer_kernel<2><<<layerBlocks, 256, 0, stream>>>(B2, nullptr, row_ptr, edges, n2,
                                                     E, B1, acc, nullptr);
}

// Round 3
// 977.873 us; speedup vs baseline: 1.3089x; 1.0098x over previous
//
#include <hip/hip_runtime.h>

#define NUM_USERS 100000
#define NUM_ITEMS 150000
#define N_NODES   250000
#define DIM       64
#define N_EDGES   2000000
#define EPS       0.2

#define SCAN_BS 1024
#define SCAN_NB ((N_NODES + SCAN_BS - 1) / SCAN_BS)   // 245

// ---------------------------------------------------------------------------
// CSR build: histogram of dst
// ---------------------------------------------------------------------------
__global__ void hist_kernel(const int* __restrict__ dst, int* __restrict__ counts) {
    int e = blockIdx.x * blockDim.x + threadIdx.x;
    if (e >= N_EDGES) return;
    atomicAdd(&counts[dst[e]], 1);
}

// in-place inclusive scan per 1024-block; block totals -> bsums
__global__ void scan_block(int* __restrict__ data, int* __restrict__ bsums) {
    __shared__ int tmp[SCAN_BS];
    int gid = blockIdx.x * SCAN_BS + threadIdx.x;
    int v = (gid < N_NODES) ? data[gid] : 0;
    tmp[threadIdx.x] = v;
    __syncthreads();
    for (int off = 1; off < SCAN_BS; off <<= 1) {
        int t = (threadIdx.x >= off) ? tmp[threadIdx.x - off] : 0;
        __syncthreads();
        tmp[threadIdx.x] += t;
        __syncthreads();
    }
    if (gid < N_NODES) data[gid] = tmp[threadIdx.x];
    if (threadIdx.x == SCAN_BS - 1) bsums[blockIdx.x] = tmp[SCAN_BS - 1];
}

// row_ptr[i+1] = incl[i] + exclusive_scan(bsums)[block(i)]; row_ptr[0] = 0.
// Also seeds cursor[] (= row starts) for fill_kernel, so no D2D copy and no
// second memset are needed. The 245-entry bsums scan is done redundantly per
// block by wave 0 (shfl scan) -- replaces the old single-thread serial
// scan_bsums kernel (~245 dependent global round-trips of pure latency).
__global__ void scan_finalize(const int* __restrict__ incl, const int* __restrict__ bsums,
                              int* __restrict__ row_ptr, int* __restrict__ cursor) {
    __shared__ int sbase[SCAN_NB];
    int tid = threadIdx.x;
    if (tid < 64) {
        int idx = tid * 4;
        int v0 = (idx + 0 < SCAN_NB) ? bsums[idx + 0] : 0;
        int v1 = (idx + 1 < SCAN_NB) ? bsums[idx + 1] : 0;
        int v2 = (idx + 2 < SCAN_NB) ? bsums[idx + 2] : 0;
        int v3 = (idx + 3 < SCAN_NB) ? bsums[idx + 3] : 0;
        int lsum = v0 + v1 + v2 + v3;
        int inc = lsum;
        #pragma unroll
        for (int off = 1; off < 64; off <<= 1) {
            int t = __shfl_up(inc, off);
            if (tid >= off) inc += t;
        }
        int base = inc - lsum;   // exclusive prefix of this lane's group
        if (idx + 0 < SCAN_NB) sbase[idx + 0] = base;            base += v0;
        if (idx + 1 < SCAN_NB) sbase[idx + 1] = base;            base += v1;
        if (idx + 2 < SCAN_NB) sbase[idx + 2] = base;            base += v2;
        if (idx + 3 < SCAN_NB) sbase[idx + 3] = base;
    }
    __syncthreads();
    int gid = blockIdx.x * SCAN_BS + tid;
    if (gid < N_NODES) {
        int e = incl[gid] + sbase[gid >> 10];   // inclusive prefix over all nodes
        row_ptr[gid + 1] = e;
        if (gid + 1 < N_NODES) cursor[gid + 1] = e;
    }
    if (gid == 0) { row_ptr[0] = 0; cursor[0] = 0; }
}

// scatter edges into CSR slots; cursor[] pre-seeded with row starts, so the
// atomicAdd return IS the slot (no row_ptr read inside the loop).
__global__ void fill_kernel(const int* __restrict__ src, const int* __restrict__ dst,
                            const float* __restrict__ vals,
                            int* __restrict__ cursor, int2* __restrict__ edges) {
    int e = blockIdx.x * blockDim.x + threadIdx.x;
    if (e >= N_EDGES) return;
    int pos = atomicAdd(&cursor[dst[e]], 1);
    edges[pos] = make_int2(src[e], __float_as_int(vals[e]));
}

// ---------------------------------------------------------------------------
// fused layer: one 64-lane wave per node (lane == dim)
//   seg = sum over in-edges of val * X[src][lane]   (fp32 loads, fp64 accum)
//     MODE 0: X = concat(user, item) read directly from the inputs
//     MODE 1/2: X = Ain
//   ne  = seg + sign(seg) * l2norm(noise_row) * EPS
//   MODE 0: Aout = ne; cl_out = l2norm(ne)
//   MODE 1: Aout = ne
//   MODE 2: a = E(user/item) + Bprev + Ain + ne; out = l2norm(a)
// ---------------------------------------------------------------------------
template<int MODE>
__global__ __launch_bounds__(256) void layer_kernel(
        const float* __restrict__ Ain,
        float* __restrict__ Aout,
        const float* __restrict__ Bprev,
        const int* __restrict__ row_ptr,
        const int2* __restrict__ edges,
        const float* __restrict__ noise,
        const float* __restrict__ userp,
        const float* __restrict__ itemp,
        float* __restrict__ out,
        float* __restrict__ cl_out) {
    int node = blockIdx.x * 4 + (threadIdx.x >> 6);
    int lane = threadIdx.x & 63;
    if (node >= N_NODES) return;
    int base = node * DIM + lane;                      // < 16M, fits int

    // item rows indexed by global node id (valid for id >= NUM_USERS)
    const float* itemS = itemp - (size_t)NUM_USERS * DIM;

    int beg = row_ptr[node];
    int end = row_ptr[node + 1];

    double s0 = 0.0, s1 = 0.0, s2 = 0.0, s3 = 0.0;

    auto G = [&](int sIdx, int vbits) -> double {
        unsigned off = ((unsigned)sIdx << 6) + (unsigned)lane;   // 32-bit offset
        const float* b = (MODE == 0) ? ((sIdx < NUM_USERS) ? userp : itemS) : Ain;
        return (double)__int_as_float(vbits) * (double)b[off];
    };

    int j = beg;
    if ((j & 1) && j < end) {                          // align to int4 pairs
        int2 e = edges[j];
        s0 += G(e.x, e.y);
        ++j;
    }
    const int4* e4 = (const int4*)edges;
    int p = j >> 1;
    for (; j + 7 < end; j += 8, p += 4) {
        int4 a = e4[p], b = e4[p + 1], c = e4[p + 2], d = e4[p + 3];
        s0 += G(a.x, a.y);
        s1 += G(a.z, a.w);
        s2 += G(b.x, b.y);
        s3 += G(b.z, b.w);
        s0 += G(c.x, c.y);
        s1 += G(c.z, c.w);
        s2 += G(d.x, d.y);
        s3 += G(d.z, d.w);
    }
    for (; j + 1 < end; j += 2, ++p) {
        int4 a = e4[p];
        s0 += G(a.x, a.y);
        s1 += G(a.z, a.w);
    }
    if (j < end) {
        int2 e = edges[j];
        s0 += G(e.x, e.y);
    }
    double seg = (s0 + s1) + (s2 + s3);

    // noise row l2norm (fp32 reduce: reference computes this in fp32)
    float nzf = __builtin_nontemporal_load(noise + base);
    float ssf = nzf * nzf;
    #pragma unroll
    for (int off = 32; off; off >>= 1) ssf += __shfl_xor(ssf, off);
    double nrm = (double)(nzf * (1.0f / sqrtf(fmaxf(ssf, 1e-24f))));

    double sg = (seg > 0.0) ? 1.0 : ((seg < 0.0) ? -1.0 : 0.0);
    double ne = seg + sg * nrm * EPS;

    if (MODE != 2) Aout[base] = (float)ne;

    if (MODE == 0) {
        float nef = (float)ne;
        float s2f = nef * nef;
        #pragma unroll
        for (int off = 32; off; off >>= 1) s2f += __shfl_xor(s2f, off);
        __builtin_nontemporal_store(nef * (1.0f / sqrtf(fmaxf(s2f, 1e-24f))),
                                    cl_out + base);
    }

    if (MODE == 2) {
        float e0 = (node < NUM_USERS) ? userp[base] : itemS[base];
        double a = (double)e0 + (double)Bprev[base] + (double)Ain[base] + ne;
        float af = (float)a;
        float s3f = af * af;
        #pragma unroll
        for (int off = 32; off; off >>= 1) s3f += __shfl_xor(s3f, off);
        __builtin_nontemporal_store(af * (1.0f / sqrtf(fmaxf(s3f, 1e-24f))),
                                    out + base);
    }
}

extern "C" void kernel_launch(void* const* d_in, const int* in_sizes, int n_in,
                              void* d_out, int out_size, void* d_ws, size_t ws_size,
                              hipStream_t stream) {
    const float* user  = (const float*)d_in[0];
    const float* item  = (const float*)d_in[1];
    const float* vals  = (const float*)d_in[2];
    const float* noise = (const float*)d_in[3];
    const int*   src   = (const int*)d_in[4];
    const int*   dst   = (const int*)d_in[5];

    float* out = (float*)d_out;
    float* acc = out;                                  // 16M fp32 (users+items normalized)
    float* cl  = out + (long long)N_NODES * DIM;       // 16M fp32 (cl region)

    char* p = (char*)d_ws;
    float* B1 = (float*)p;  p += (size_t)N_NODES * DIM * sizeof(float);   // 64 MB
    float* B2 = (float*)p;  p += (size_t)N_NODES * DIM * sizeof(float);   // 64 MB
    int* row_ptr = (int*)p;   p += ((size_t)(N_NODES + 1) * 4 + 255) & ~255ull;
    int* fill    = (int*)p;   p += ((size_t)N_NODES * 4 + 255) & ~255ull;
    int* bsums   = (int*)p;   p += 4096;
    int2* edges  = (int2*)p;                                              // 16 MB

    const int edgeBlocks = (N_EDGES + 255) / 256;      // 7813

    // --- CSR build ---
    hipMemsetAsync(fill, 0, (size_t)N_NODES * 4, stream);
    hist_kernel<<<edgeBlocks, 256, 0, stream>>>(dst, fill);
    scan_block<<<SCAN_NB, SCAN_BS, 0, stream>>>(fill, bsums);
    scan_finalize<<<SCAN_NB, SCAN_BS, 0, stream>>>(fill, bsums, row_ptr, fill);
    fill_kernel<<<edgeBlocks, 256, 0, stream>>>(src, dst, vals, fill, edges);

    // --- 3 fused layers: (user,item) -> B1 -> B2 -> finalize ---
    const int layerBlocks = (N_NODES + 3) / 4;         // 62500 (4 waves/block)
    const float* n0 = noise;
    const float* n1 = noise + (long long)N_NODES * DIM;
    const float* n2 = noise + 2LL * N_NODES * DIM;
    layer_kernel<0><<<layerBlocks, 256, 0, stream>>>(nullptr, B1, nullptr, row_ptr, edges,
                                                     n0, user, item, nullptr, cl);
    layer_kernel<1><<<layerBlocks, 256, 0, stream>>>(B1, B2, nullptr, row_ptr, edges,
                                                     n1, user, item, nullptr, nullptr);
    layer_kernel<2><<<layerBlocks, 256, 0, stream>>>(B2, nullptr, B1, row_ptr, edges,
                                                     n2, user, item, acc, nullptr);
}

// Round 4
// 898.227 us; speedup vs baseline: 1.4250x; 1.0887x over previous
//
#include <hip/hip_runtime.h>

#define NUM_USERS 100000
#define NUM_ITEMS 150000
#define N_NODES   250000
#define DIM       64
#define N_EDGES   2000000
#define EPS       0.2

#define SCAN_BS 1024
#define SCAN_NB ((N_NODES + SCAN_BS - 1) / SCAN_BS)   // 245

// ---------------------------------------------------------------------------
// CSR build: histogram of dst
// ---------------------------------------------------------------------------
__global__ void hist_kernel(const int* __restrict__ dst, int* __restrict__ counts) {
    int e = blockIdx.x * blockDim.x + threadIdx.x;
    if (e >= N_EDGES) return;
    atomicAdd(&counts[dst[e]], 1);
}

// in-place inclusive scan per 1024-block; block totals -> bsums
__global__ void scan_block(int* __restrict__ data, int* __restrict__ bsums) {
    __shared__ int tmp[SCAN_BS];
    int gid = blockIdx.x * SCAN_BS + threadIdx.x;
    int v = (gid < N_NODES) ? data[gid] : 0;
    tmp[threadIdx.x] = v;
    __syncthreads();
    for (int off = 1; off < SCAN_BS; off <<= 1) {
        int t = (threadIdx.x >= off) ? tmp[threadIdx.x - off] : 0;
        __syncthreads();
        tmp[threadIdx.x] += t;
        __syncthreads();
    }
    if (gid < N_NODES) data[gid] = tmp[threadIdx.x];
    if (threadIdx.x == SCAN_BS - 1) bsums[blockIdx.x] = tmp[SCAN_BS - 1];
}

// row_ptr[i+1] = incl[i] + exclusive_scan(bsums)[block(i)]; row_ptr[0] = 0.
// Also seeds cursor[] (= row starts) for fill_kernel. The 245-entry bsums
// scan is done redundantly per block by wave 0 (shfl scan).
__global__ void scan_finalize(const int* __restrict__ incl, const int* __restrict__ bsums,
                              int* __restrict__ row_ptr, int* __restrict__ cursor) {
    __shared__ int sbase[SCAN_NB];
    int tid = threadIdx.x;
    if (tid < 64) {
        int idx = tid * 4;
        int v0 = (idx + 0 < SCAN_NB) ? bsums[idx + 0] : 0;
        int v1 = (idx + 1 < SCAN_NB) ? bsums[idx + 1] : 0;
        int v2 = (idx + 2 < SCAN_NB) ? bsums[idx + 2] : 0;
        int v3 = (idx + 3 < SCAN_NB) ? bsums[idx + 3] : 0;
        int lsum = v0 + v1 + v2 + v3;
        int inc = lsum;
        #pragma unroll
        for (int off = 1; off < 64; off <<= 1) {
            int t = __shfl_up(inc, off);
            if (tid >= off) inc += t;
        }
        int base = inc - lsum;   // exclusive prefix of this lane's group
        if (idx + 0 < SCAN_NB) sbase[idx + 0] = base;            base += v0;
        if (idx + 1 < SCAN_NB) sbase[idx + 1] = base;            base += v1;
        if (idx + 2 < SCAN_NB) sbase[idx + 2] = base;            base += v2;
        if (idx + 3 < SCAN_NB) sbase[idx + 3] = base;
    }
    __syncthreads();
    int gid = blockIdx.x * SCAN_BS + tid;
    if (gid < N_NODES) {
        int e = incl[gid] + sbase[gid >> 10];   // inclusive prefix over all nodes
        row_ptr[gid + 1] = e;
        if (gid + 1 < N_NODES) cursor[gid + 1] = e;
    }
    if (gid == 0) { row_ptr[0] = 0; cursor[0] = 0; }
}

// scatter edges into CSR slots; cursor[] pre-seeded with row starts, so the
// atomicAdd return IS the slot (no row_ptr read inside the loop).
__global__ void fill_kernel(const int* __restrict__ src, const int* __restrict__ dst,
                            const float* __restrict__ vals,
                            int* __restrict__ cursor, int2* __restrict__ edges) {
    int e = blockIdx.x * blockDim.x + threadIdx.x;
    if (e >= N_EDGES) return;
    int pos = atomicAdd(&cursor[dst[e]], 1);
    edges[pos] = make_int2(src[e], __float_as_int(vals[e]));
}

// ---------------------------------------------------------------------------
// fused layer: one 64-lane wave per node (lane == dim)
//   seg = sum over in-edges of val * X[src][lane]   (fp32 loads, fp64 accum)
//     MODE 0: X = concat(user, item) read directly from the inputs
//     MODE 1/2: X = Ain
//   ne  = seg + sign(seg) * l2norm(noise_row) * EPS
//   MODE 0: Aout = ne; cl_out = l2norm(ne)
//   MODE 1: Aout = ne
//   MODE 2: a = E(user/item) + Bprev + Ain + ne; out = l2norm(a)
//
// All edge-list state (beg/end/j/p, edge words) is forced wave-uniform via
// readfirstlane so the compiler emits SALU loop control + s_load edge reads
// + scalar gather bases; the VALU does only cvt/fma and the VMEM pipe only
// per-lane gathers.
// ---------------------------------------------------------------------------
template<int MODE>
__global__ __launch_bounds__(256) void layer_kernel(
        const float* __restrict__ Ain,
        float* __restrict__ Aout,
        const float* __restrict__ Bprev,
        const int* __restrict__ row_ptr,
        const int2* __restrict__ edges,
        const float* __restrict__ noise,
        const float* __restrict__ userp,
        const float* __restrict__ itemp,
        float* __restrict__ out,
        float* __restrict__ cl_out) {
    int node = blockIdx.x * 4 + (threadIdx.x >> 6);
    int lane = threadIdx.x & 63;
    if (node >= N_NODES) return;
    int base = node * DIM + lane;                      // < 16M, fits int

    // item rows indexed by global node id (valid for id >= NUM_USERS)
    const float* itemS = itemp - (size_t)NUM_USERS * DIM;

    int beg = __builtin_amdgcn_readfirstlane(row_ptr[node]);
    int end = __builtin_amdgcn_readfirstlane(row_ptr[node + 1]);

    double s0 = 0.0, s1 = 0.0, s2 = 0.0, s3 = 0.0;

    // sIdx/vbits are wave-uniform scalars; only the gather itself is vector.
    auto G = [&](int sIdx, int vbits) -> double {
        const float* b = (MODE == 0) ? ((sIdx < NUM_USERS) ? userp : itemS) : Ain;
        unsigned off = ((unsigned)sIdx << 6) + (unsigned)lane;
        return (double)__int_as_float(vbits) * (double)b[off];
    };

    int j = beg;
    if ((j & 1) && j < end) {                          // align to int4 pairs
        int2 e = edges[j];
        s0 += G(e.x, e.y);
        ++j;
    }
    const int4* e4 = (const int4*)edges;
    int p = j >> 1;
    for (; j + 7 < end; j += 8, p += 4) {
        int4 a = e4[p], b = e4[p + 1], c = e4[p + 2], d = e4[p + 3];
        s0 += G(a.x, a.y);
        s1 += G(a.z, a.w);
        s2 += G(b.x, b.y);
        s3 += G(b.z, b.w);
        s0 += G(c.x, c.y);
        s1 += G(c.z, c.w);
        s2 += G(d.x, d.y);
        s3 += G(d.z, d.w);
    }
    for (; j + 1 < end; j += 2, ++p) {
        int4 a = e4[p];
        s0 += G(a.x, a.y);
        s1 += G(a.z, a.w);
    }
    if (j < end) {
        int2 e = edges[j];
        s0 += G(e.x, e.y);
    }
    double seg = (s0 + s1) + (s2 + s3);

    // noise row l2norm (fp32 reduce: reference computes this in fp32)
    float nzf = __builtin_nontemporal_load(noise + base);
    float ssf = nzf * nzf;
    #pragma unroll
    for (int off = 32; off; off >>= 1) ssf += __shfl_xor(ssf, off);
    double nrm = (double)(nzf * (1.0f / sqrtf(fmaxf(ssf, 1e-24f))));

    double sg = (seg > 0.0) ? 1.0 : ((seg < 0.0) ? -1.0 : 0.0);
    double ne = seg + sg * nrm * EPS;

    if (MODE != 2) Aout[base] = (float)ne;

    if (MODE == 0) {
        float nef = (float)ne;
        float s2f = nef * nef;
        #pragma unroll
        for (int off = 32; off; off >>= 1) s2f += __shfl_xor(s2f, off);
        __builtin_nontemporal_store(nef * (1.0f / sqrtf(fmaxf(s2f, 1e-24f))),
                                    cl_out + base);
    }

    if (MODE == 2) {
        float e0 = (node < NUM_USERS) ? userp[base] : itemS[base];
        double a = (double)e0 + (double)Bprev[base] + (double)Ain[base] + ne;
        float af = (float)a;
        float s3f = af * af;
        #pragma unroll
        for (int off = 32; off; off >>= 1) s3f += __shfl_xor(s3f, off);
        __builtin_nontemporal_store(af * (1.0f / sqrtf(fmaxf(s3f, 1e-24f))),
                                    out + base);
    }
}

extern "C" void kernel_launch(void* const* d_in, const int* in_sizes, int n_in,
                              void* d_out, int out_size, void* d_ws, size_t ws_size,
                              hipStream_t stream) {
    const float* user  = (const float*)d_in[0];
    const float* item  = (const float*)d_in[1];
    const float* vals  = (const float*)d_in[2];
    const float* noise = (const float*)d_in[3];
    const int*   src   = (const int*)d_in[4];
    const int*   dst   = (const int*)d_in[5];

    float* out = (float*)d_out;
    float* acc = out;                                  // 16M fp32 (users+items normalized)
    float* cl  = out + (long long)N_NODES * DIM;       // 16M fp32 (cl region)

    char* p = (char*)d_ws;
    float* B1 = (float*)p;  p += (size_t)N_NODES * DIM * sizeof(float);   // 64 MB
    float* B2 = (float*)p;  p += (size_t)N_NODES * DIM * sizeof(float);   // 64 MB
    int* row_ptr = (int*)p;   p += ((size_t)(N_NODES + 1) * 4 + 255) & ~255ull;
    int* fill    = (int*)p;   p += ((size_t)N_NODES * 4 + 255) & ~255ull;
    int* bsums   = (int*)p;   p += 4096;
    int2* edges  = (int2*)p;                                              // 16 MB

    const int edgeBlocks = (N_EDGES + 255) / 256;      // 7813

    // --- CSR build ---
    hipMemsetAsync(fill, 0, (size_t)N_NODES * 4, stream);
    hist_kernel<<<edgeBlocks, 256, 0, stream>>>(dst, fill);
    scan_block<<<SCAN_NB, SCAN_BS, 0, stream>>>(fill, bsums);
    scan_finalize<<<SCAN_NB, SCAN_BS, 0, stream>>>(fill, bsums, row_ptr, fill);
    fill_kernel<<<edgeBlocks, 256, 0, stream>>>(src, dst, vals, fill, edges);

    // --- 3 fused layers: (user,item) -> B1 -> B2 -> finalize ---
    const int layerBlocks = (N_NODES + 3) / 4;         // 62500 (4 waves/block)
    const float* n0 = noise;
    const float* n1 = noise + (long long)N_NODES * DIM;
    const float* n2 = noise + 2LL * N_NODES * DIM;
    layer_kernel<0><<<layerBlocks, 256, 0, stream>>>(nullptr, B1, nullptr, row_ptr, edges,
                                                     n0, user, item, nullptr, cl);
    layer_kernel<1><<<layerBlocks, 256, 0, stream>>>(B1, B2, nullptr, row_ptr, edges,
                                                     n1, user, item, nullptr, nullptr);
    layer_kernel<2><<<layerBlocks, 256, 0, stream>>>(B2, nullptr, B1, row_ptr, edges,
                                                     n2, user, item, acc, nullptr);
}

// Round 5
// 767.002 us; speedup vs baseline: 1.6688x; 1.1711x over previous
//
#include <hip/hip_runtime.h>

#define NUM_USERS 100000
#define NUM_ITEMS 150000
#define N_NODES   250000
#define DIM       64
#define N_EDGES   2000000
#define EPS       0.2

// ---- bucketed CSR build parameters ----
#define BK_SHIFT  9
#define BK_NODES  512
#define NBK       ((N_NODES + BK_NODES - 1) / BK_NODES)   // 489
#define CNT_BLOCKS 256
#define CNT_TILE  ((N_EDGES + CNT_BLOCKS - 1) / CNT_BLOCKS) // 7813

// ---------------------------------------------------------------------------
// Pass A.1: per-bucket edge counts (LDS-aggregated histogram)
// ---------------------------------------------------------------------------
__global__ __launch_bounds__(256) void bucket_count(const int* __restrict__ dst,
                                                    int* __restrict__ bcnt) {
    __shared__ int h[NBK];
    for (int i = threadIdx.x; i < NBK; i += 256) h[i] = 0;
    __syncthreads();
    int start = blockIdx.x * CNT_TILE;
    int end   = min(start + CNT_TILE, N_EDGES);
    for (int e = start + threadIdx.x; e < end; e += 256)
        atomicAdd(&h[dst[e] >> BK_SHIFT], 1);
    __syncthreads();
    for (int i = threadIdx.x; i < NBK; i += 256) {
        int v = h[i];
        if (v) atomicAdd(&bcnt[i], v);
    }
}

// ---------------------------------------------------------------------------
// Pass A.2: exclusive scan of 489 bucket counts (one wave, 8 per lane)
// -> bptr[NBK+1], and seeds the scatter cursor bcur[]
// ---------------------------------------------------------------------------
__global__ void bucket_scan(const int* __restrict__ bcnt,
                            int* __restrict__ bptr, int* __restrict__ bcur) {
    int lane = threadIdx.x;            // launched with 64 threads
    int idx = lane * 8;
    int v[8]; int lsum = 0;
    #pragma unroll
    for (int k = 0; k < 8; ++k) { v[k] = (idx + k < NBK) ? bcnt[idx + k] : 0; lsum += v[k]; }
    int inc = lsum;
    #pragma unroll
    for (int off = 1; off < 64; off <<= 1) {
        int t = __shfl_up(inc, off);
        if (lane >= off) inc += t;
    }
    int base = inc - lsum;             // exclusive prefix of this lane's group
    #pragma unroll
    for (int k = 0; k < 8; ++k) {
        if (idx + k < NBK) { bptr[idx + k] = base; bcur[idx + k] = base; }
        base += v[k];
    }
    if (lane == 63) bptr[NBK] = base;  // == N_EDGES
}

// ---------------------------------------------------------------------------
// Pass A.3: scatter edges into bucket regions of tmp[].
// Per-block LDS hist -> one reservation atomic per (block,bucket) -> LDS
// cursors hand out slots. All writes to a given line come from ONE block
// (one XCD), so lines are assembled in that XCD's L2 and written back full —
// kills the 127 MB write-allocate waste of the old random scatter.
// Payload: {src | dstLocal<<18, val_bits}  (src < 2^18, dstLocal < 2^9)
// ---------------------------------------------------------------------------
__global__ __launch_bounds__(256) void bucket_scatter(const int* __restrict__ src,
                                                      const int* __restrict__ dst,
                                                      const float* __restrict__ vals,
                                                      int* __restrict__ bcur,
                                                      int2* __restrict__ tmp) {
    __shared__ int h[NBK];
    for (int i = threadIdx.x; i < NBK; i += 256) h[i] = 0;
    __syncthreads();
    int start = blockIdx.x * CNT_TILE;
    int end   = min(start + CNT_TILE, N_EDGES);
    for (int e = start + threadIdx.x; e < end; e += 256)
        atomicAdd(&h[dst[e] >> BK_SHIFT], 1);
    __syncthreads();
    for (int i = threadIdx.x; i < NBK; i += 256) {
        int v = h[i];
        h[i] = v ? atomicAdd(&bcur[i], v) : 0;   // reserve; h[] becomes cursor base
    }
    __syncthreads();
    for (int e = start + threadIdx.x; e < end; e += 256) {
        int d = dst[e];
        int slot = atomicAdd(&h[d >> BK_SHIFT], 1);
        tmp[slot] = make_int2(src[e] | ((d & (BK_NODES - 1)) << 18),
                              __float_as_int(vals[e]));
    }
}

// ---------------------------------------------------------------------------
// Pass B: one block per bucket. Local node histogram + wave-scan -> writes
// row_ptr (coalesced) and scatters edges to final CSR slots. The bucket's
// output region (~32 KB) is owned by this block alone -> full-line writebacks.
// ---------------------------------------------------------------------------
__global__ __launch_bounds__(256) void bucket_build(const int2* __restrict__ tmp,
                                                    const int* __restrict__ bptr,
                                                    int* __restrict__ row_ptr,
                                                    int2* __restrict__ edges) {
    int b = blockIdx.x;
    int s = bptr[b], e = bptr[b + 1];
    __shared__ int cnt[BK_NODES];
    __shared__ int off[BK_NODES];
    for (int i = threadIdx.x; i < BK_NODES; i += 256) cnt[i] = 0;
    __syncthreads();
    for (int k = s + threadIdx.x; k < e; k += 256)
        atomicAdd(&cnt[tmp[k].x >> 18], 1);
    __syncthreads();
    if (threadIdx.x < 64) {            // wave 0: scan 512 counters, 8 per lane
        int lane = threadIdx.x;
        int idx = lane * 8;
        int v[8]; int lsum = 0;
        #pragma unroll
        for (int k = 0; k < 8; ++k) { v[k] = cnt[idx + k]; lsum += v[k]; }
        int inc = lsum;
        #pragma unroll
        for (int o = 1; o < 64; o <<= 1) {
            int t = __shfl_up(inc, o);
            if (lane >= o) inc += t;
        }
        int base = inc - lsum;
        #pragma unroll
        for (int k = 0; k < 8; ++k) { off[idx + k] = base; base += v[k]; }
    }
    __syncthreads();
    for (int i = threadIdx.x; i < BK_NODES; i += 256) {
        int g = (b << BK_SHIFT) + i;
        if (g < N_NODES) row_ptr[g] = s + off[i];
        cnt[i] = off[i];               // reset as scatter cursor
    }
    if (b == 0 && threadIdx.x == 0) row_ptr[N_NODES] = N_EDGES;
    __syncthreads();
    for (int k = s + threadIdx.x; k < e; k += 256) {
        int2 t = tmp[k];
        int loc = t.x >> 18;
        int pos = atomicAdd(&cnt[loc], 1);
        edges[s + pos] = make_int2(t.x & 0x3FFFF, t.y);
    }
}

// ---------------------------------------------------------------------------
// fused layer: one 64-lane wave per node (lane == dim)  [unchanged, round 4]
//   seg = sum over in-edges of val * X[src][lane]   (fp32 loads, fp64 accum)
//     MODE 0: X = concat(user, item) read directly from the inputs
//     MODE 1/2: X = Ain
//   ne  = seg + sign(seg) * l2norm(noise_row) * EPS
//   MODE 0: Aout = ne; cl_out = l2norm(ne)
//   MODE 1: Aout = ne
//   MODE 2: a = E(user/item) + Bprev + Ain + ne; out = l2norm(a)
// Edge-list state forced wave-uniform via readfirstlane -> SALU loop control,
// s_load edge reads, scalar gather bases; VALU does only cvt/fma.
// ---------------------------------------------------------------------------
template<int MODE>
__global__ __launch_bounds__(256) void layer_kernel(
        const float* __restrict__ Ain,
        float* __restrict__ Aout,
        const float* __restrict__ Bprev,
        const int* __restrict__ row_ptr,
        const int2* __restrict__ edges,
        const float* __restrict__ noise,
        const float* __restrict__ userp,
        const float* __restrict__ itemp,
        float* __restrict__ out,
        float* __restrict__ cl_out) {
    int node = blockIdx.x * 4 + (threadIdx.x >> 6);
    int lane = threadIdx.x & 63;
    if (node >= N_NODES) return;
    int base = node * DIM + lane;                      // < 16M, fits int

    // item rows indexed by global node id (valid for id >= NUM_USERS)
    const float* itemS = itemp - (size_t)NUM_USERS * DIM;

    int beg = __builtin_amdgcn_readfirstlane(row_ptr[node]);
    int end = __builtin_amdgcn_readfirstlane(row_ptr[node + 1]);

    double s0 = 0.0, s1 = 0.0, s2 = 0.0, s3 = 0.0;

    auto G = [&](int sIdx, int vbits) -> double {
        const float* b = (MODE == 0) ? ((sIdx < NUM_USERS) ? userp : itemS) : Ain;
        unsigned off = ((unsigned)sIdx << 6) + (unsigned)lane;
        return (double)__int_as_float(vbits) * (double)b[off];
    };

    int j = beg;
    if ((j & 1) && j < end) {                          // align to int4 pairs
        int2 e = edges[j];
        s0 += G(e.x, e.y);
        ++j;
    }
    const int4* e4 = (const int4*)edges;
    int p = j >> 1;
    for (; j + 7 < end; j += 8, p += 4) {
        int4 a = e4[p], b = e4[p + 1], c = e4[p + 2], d = e4[p + 3];
        s0 += G(a.x, a.y);
        s1 += G(a.z, a.w);
        s2 += G(b.x, b.y);
        s3 += G(b.z, b.w);
        s0 += G(c.x, c.y);
        s1 += G(c.z, c.w);
        s2 += G(d.x, d.y);
        s3 += G(d.z, d.w);
    }
    for (; j + 1 < end; j += 2, ++p) {
        int4 a = e4[p];
        s0 += G(a.x, a.y);
        s1 += G(a.z, a.w);
    }
    if (j < end) {
        int2 e = edges[j];
        s0 += G(e.x, e.y);
    }
    double seg = (s0 + s1) + (s2 + s3);

    // noise row l2norm (fp32 reduce: reference computes this in fp32)
    float nzf = __builtin_nontemporal_load(noise + base);
    float ssf = nzf * nzf;
    #pragma unroll
    for (int off = 32; off; off >>= 1) ssf += __shfl_xor(ssf, off);
    double nrm = (double)(nzf * (1.0f / sqrtf(fmaxf(ssf, 1e-24f))));

    double sg = (seg > 0.0) ? 1.0 : ((seg < 0.0) ? -1.0 : 0.0);
    double ne = seg + sg * nrm * EPS;

    if (MODE != 2) Aout[base] = (float)ne;

    if (MODE == 0) {
        float nef = (float)ne;
        float s2f = nef * nef;
        #pragma unroll
        for (int off = 32; off; off >>= 1) s2f += __shfl_xor(s2f, off);
        __builtin_nontemporal_store(nef * (1.0f / sqrtf(fmaxf(s2f, 1e-24f))),
                                    cl_out + base);
    }

    if (MODE == 2) {
        float e0 = (node < NUM_USERS) ? userp[base] : itemS[base];
        double a = (double)e0 + (double)Bprev[base] + (double)Ain[base] + ne;
        float af = (float)a;
        float s3f = af * af;
        #pragma unroll
        for (int off = 32; off; off >>= 1) s3f += __shfl_xor(s3f, off);
        __builtin_nontemporal_store(af * (1.0f / sqrtf(fmaxf(s3f, 1e-24f))),
                                    out + base);
    }
}

extern "C" void kernel_launch(void* const* d_in, const int* in_sizes, int n_in,
                              void* d_out, int out_size, void* d_ws, size_t ws_size,
                              hipStream_t stream) {
    const float* user  = (const float*)d_in[0];
    const float* item  = (const float*)d_in[1];
    const float* vals  = (const float*)d_in[2];
    const float* noise = (const float*)d_in[3];
    const int*   src   = (const int*)d_in[4];
    const int*   dst   = (const int*)d_in[5];

    float* out = (float*)d_out;
    float* acc = out;                                  // 16M fp32 (users+items normalized)
    float* cl  = out + (long long)N_NODES * DIM;       // 16M fp32 (cl region)

    char* p = (char*)d_ws;
    float* B1 = (float*)p;  p += (size_t)N_NODES * DIM * sizeof(float);   // 64 MB
    float* B2 = (float*)p;  p += (size_t)N_NODES * DIM * sizeof(float);   // 64 MB
    int* row_ptr = (int*)p;   p += ((size_t)(N_NODES + 1) * 4 + 255) & ~255ull;
    int* bcnt    = (int*)p;   p += 2048;               // NBK ints
    int* bptr    = (int*)p;   p += 2048;               // NBK+1 ints
    int* bcur    = (int*)p;   p += 2048;               // NBK ints
    int2* tmp    = (int2*)p;  p += (size_t)N_EDGES * 8;                   // 16 MB
    int2* edges  = (int2*)p;                                              // 16 MB

    // --- CSR build (bucketed two-pass counting sort) ---
    hipMemsetAsync(bcnt, 0, NBK * sizeof(int), stream);
    bucket_count  <<<CNT_BLOCKS, 256, 0, stream>>>(dst, bcnt);
    bucket_scan   <<<1, 64, 0, stream>>>(bcnt, bptr, bcur);
    bucket_scatter<<<CNT_BLOCKS, 256, 0, stream>>>(src, dst, vals, bcur, tmp);
    bucket_build  <<<NBK, 256, 0, stream>>>(tmp, bptr, row_ptr, edges);

    // --- 3 fused layers: (user,item) -> B1 -> B2 -> finalize ---
    const int layerBlocks = (N_NODES + 3) / 4;         // 62500 (4 waves/block)
    const float* n0 = noise;
    const float* n1 = noise + (long long)N_NODES * DIM;
    const float* n2 = noise + 2LL * N_NODES * DIM;
    layer_kernel<0><<<layerBlocks, 256, 0, stream>>>(nullptr, B1, nullptr, row_ptr, edges,
                                                     n0, user, item, nullptr, cl);
    layer_kernel<1><<<layerBlocks, 256, 0, stream>>>(B1, B2, nullptr, row_ptr, edges,
                                                     n1, user, item, nullptr, nullptr);
    layer_kernel<2><<<layerBlocks, 256, 0, stream>>>(B2, nullptr, B1, row_ptr, edges,
                                                     n2, user, item, acc, nullptr);
}